// Round 11
// baseline (100.481 us; speedup 1.0000x reference)
//
#include <hip/hip_runtime.h>
#include <hip/hip_bf16.h>

#define B_   8
#define LQ_  128
#define LK_  1024
#define H_   128

// BSS scratch. tanh(q+k) = 1 - 2/(EQ*EK + 1) with EQ=exp(2q'), EK=exp(2k').
__device__ float g_eq[B_ * LQ_ * H_];
__device__ float g_ek[B_ * LK_ * H_];
__device__ float g_sc[B_ * LQ_ * LK_];   // raw scores, only [0,valid) written

#define C2LOG2E 2.8853900817779268f      // 2/ln2

// Tiled projection (proven R8-R10), epilogue writes exp(2*acc).
__global__ __launch_bounds__(256) void proj_kernel(const float* __restrict__ q,
                                                   const float* __restrict__ k,
                                                   const float* __restrict__ Wq,
                                                   const float* __restrict__ Wk) {
    __shared__ float Ws[H_ * H_];
    __shared__ float Xs[32 * H_];
    const int t = threadIdx.x;
    const int tile = blockIdx.x;
    const float* X; const float* W; float* Y; int r0;
    if (tile < 32) { X = q; W = Wq; Y = g_eq; r0 = tile * 32; }
    else           { X = k; W = Wk; Y = g_ek; r0 = (tile - 32) * 32; }

    #pragma unroll
    for (int u = 0; u < 16; ++u) {
        int idx = u * 256 + t;
        *(float4*)(Ws + idx * 4) = *(const float4*)(W + idx * 4);
    }
    #pragma unroll
    for (int u = 0; u < 4; ++u) {
        int idx = u * 256 + t;
        int r = idx >> 5, c = idx & 31;
        *(float4*)(Xs + r * H_ + c * 4) = *(const float4*)(X + (r0 + r) * H_ + c * 4);
    }
    __syncthreads();

    const int r4 = t >> 5;
    const int c4 = t & 31;
    float acc[4][4] = {};
    #pragma unroll 4
    for (int kk = 0; kk < H_; ++kk) {
        float4 w4 = *(const float4*)(Ws + kk * H_ + c4 * 4);
        #pragma unroll
        for (int i = 0; i < 4; ++i) {
            float x = Xs[(r4 * 4 + i) * H_ + kk];
            acc[i][0] = fmaf(x, w4.x, acc[i][0]);
            acc[i][1] = fmaf(x, w4.y, acc[i][1]);
            acc[i][2] = fmaf(x, w4.z, acc[i][2]);
            acc[i][3] = fmaf(x, w4.w, acc[i][3]);
        }
    }
    #pragma unroll
    for (int i = 0; i < 4; ++i) {
        float4 o;
        o.x = __builtin_amdgcn_exp2f(acc[i][0] * C2LOG2E);
        o.y = __builtin_amdgcn_exp2f(acc[i][1] * C2LOG2E);
        o.z = __builtin_amdgcn_exp2f(acc[i][2] * C2LOG2E);
        o.w = __builtin_amdgcn_exp2f(acc[i][3] * C2LOG2E);
        *(float4*)(Y + (r0 + r4 * 4 + i) * H_ + c4 * 4) = o;
    }
}

// Scores: grid 2048 = (row = blk>>1, half = blk&1), 128 threads.
// Thread owns 4 ADJACENT s-rows (s0 = half*512 + 4t): 4 independent e-load
// streams for MLP; q/w held in registers per 16-elem h-chunk (uniform loads,
// no LDS). Masked-row loads are in-bounds garbage, never written (nj guard).
// score = wsum - 2 * sum_h w_h * rcp(EQ_h*EK_h + 1).
__global__ __launch_bounds__(128) void score_kernel(const int* __restrict__ valid_lens,
                                                    const float* __restrict__ w_v) {
    const int blk = blockIdx.x;
    const int row = blk >> 1;                 // b*128 + l
    const int base = (blk & 1) << 9;          // 0 | 512
    const int b = row >> 7;
    int valid = valid_lens[b];
    valid = min(max(valid, 0), LK_);
    if (base >= valid) return;                // block-uniform

    const int s0 = base + (threadIdx.x << 2);
    int nj = valid - s0;
    nj = min(max(nj, 0), 4);

    const float4* q4p = (const float4*)g_eq + (size_t)row * (H_ / 4);
    const float4* w4p = (const float4*)w_v;
    const float4* e0  = (const float4*)g_ek + ((size_t)b * LK_ + s0) * (H_ / 4);

    float a0 = 0.0f, a1 = 0.0f, a2 = 0.0f, a3 = 0.0f, wsum = 0.0f;
    #pragma unroll
    for (int c = 0; c < 8; ++c) {             // 8 chunks x 4 float4 = 128 h
        float4 qc[4], wc[4];
        #pragma unroll
        for (int i = 0; i < 4; ++i) {
            qc[i] = q4p[c * 4 + i];
            wc[i] = w4p[c * 4 + i];
            wsum += (wc[i].x + wc[i].y) + (wc[i].z + wc[i].w);
        }
        #pragma unroll
        for (int j = 0; j < 4; ++j) {
            const float4* ep = e0 + j * (H_ / 4) + c * 4;
            float aa = 0.0f;
            #pragma unroll
            for (int i = 0; i < 4; ++i) {
                float4 e = ep[i];
                aa = fmaf(wc[i].x, __builtin_amdgcn_rcpf(fmaf(qc[i].x, e.x, 1.0f)), aa);
                aa = fmaf(wc[i].y, __builtin_amdgcn_rcpf(fmaf(qc[i].y, e.y, 1.0f)), aa);
                aa = fmaf(wc[i].z, __builtin_amdgcn_rcpf(fmaf(qc[i].z, e.z, 1.0f)), aa);
                aa = fmaf(wc[i].w, __builtin_amdgcn_rcpf(fmaf(qc[i].w, e.w, 1.0f)), aa);
            }
            if (j == 0) a0 += aa;
            else if (j == 1) a1 += aa;
            else if (j == 2) a2 += aa;
            else a3 += aa;
        }
    }
    float* srow = g_sc + (size_t)row * LK_;
    float r0 = fmaf(-2.0f, a0, wsum);
    float r1 = fmaf(-2.0f, a1, wsum);
    float r2 = fmaf(-2.0f, a2, wsum);
    float r3 = fmaf(-2.0f, a3, wsum);
    if (nj == 4) {
        *(float4*)(srow + s0) = make_float4(r0, r1, r2, r3);
    } else {
        if (nj > 0) srow[s0] = r0;
        if (nj > 1) srow[s0 + 1] = r1;
        if (nj > 2) srow[s0 + 2] = r2;
    }
}

// Softmax + PV, 2 rows per block (512 blocks x 512 threads).
// Stage scores -> per-row softmax (R8-proven pattern) -> PV with values
// loaded once per float2 feeding both rows, 8-way s-split via LDS partials.
__global__ __launch_bounds__(512) void smpv_kernel(const float* __restrict__ values,
                                                   const int* __restrict__ valid_lens,
                                                   float* __restrict__ out) {
    __shared__ float sA[LK_], sB[LK_];
    __shared__ float red[8], sred[16];
    __shared__ float rinvs[2];
    __shared__ float part[8][2][H_];
    const int t = threadIdx.x;
    const int b = blockIdx.x >> 6, l0 = (blockIdx.x & 63) * 2;
    int valid = valid_lens[b];
    valid = min(max(valid, 0), LK_);

    const float* src = g_sc + (size_t)(b * LQ_ + l0) * LK_;
    for (int i = t; i < valid; i += 512) { sA[i] = src[i]; sB[i] = src[LK_ + i]; }
    __syncthreads();

    int n;
    if (valid == 0) {                         // ref: all -1e6 -> uniform
        n = LK_;
        for (int i = t; i < LK_; i += 512) { sA[i] = 1.0f; sB[i] = 1.0f; }
        if (t == 0) { rinvs[0] = 1.0f / 1024.0f; rinvs[1] = 1.0f / 1024.0f; }
    } else {
        n = valid;
        const int r = t >> 8, tt = t & 255;   // 256 threads per row
        const int w4id = tt >> 6;
        float* srow = r ? sB : sA;
        float m = -3.0e38f;
        for (int i = tt; i < n; i += 256) m = fmaxf(m, srow[i]);
        #pragma unroll
        for (int kk = 32; kk; kk >>= 1) m = fmaxf(m, __shfl_xor(m, kk, 64));
        if ((tt & 63) == 0) red[r * 4 + w4id] = m;
        __syncthreads();
        m = fmaxf(fmaxf(red[r * 4], red[r * 4 + 1]), fmaxf(red[r * 4 + 2], red[r * 4 + 3]));
        float ps = 0.0f;
        for (int i = tt; i < n; i += 256) {
            float e = __builtin_amdgcn_exp2f((srow[i] - m) * 1.44269504f);
            srow[i] = e;
            ps += e;
        }
        #pragma unroll
        for (int kk = 32; kk; kk >>= 1) ps += __shfl_xor(ps, kk, 64);
        if ((tt & 63) == 0) sred[r * 4 + w4id] = ps;
        __syncthreads();
        if (t < 2) {
            float s4 = (sred[t * 4] + sred[t * 4 + 1]) + (sred[t * 4 + 2] + sred[t * 4 + 3]);
            rinvs[t] = 1.0f / s4;
        }
    }
    __syncthreads();

    // PV: c = t>>6 in [0,8) s-chunks, v2 = t&63 float2 column.
    const int c = t >> 6;
    const int v2 = t & 63;
    const float* vb = values + (size_t)b * LK_ * H_ + 2 * v2;
    float ax0 = 0.0f, ay0 = 0.0f, ax1 = 0.0f, ay1 = 0.0f;
    #pragma unroll 4
    for (int s = c; s < n; s += 8) {
        float2 vv = *(const float2*)(vb + (size_t)s * H_);
        float w0 = sA[s], w1 = sB[s];
        ax0 = fmaf(w0, vv.x, ax0); ay0 = fmaf(w0, vv.y, ay0);
        ax1 = fmaf(w1, vv.x, ax1); ay1 = fmaf(w1, vv.y, ay1);
    }
    *(float2*)(&part[c][0][2 * v2]) = make_float2(ax0, ay0);
    *(float2*)(&part[c][1][2 * v2]) = make_float2(ax1, ay1);
    __syncthreads();
    if (t < 256) {
        const int l = t >> 7, v = t & 127;
        float o = (((part[0][l][v] + part[1][l][v]) + (part[2][l][v] + part[3][l][v]))
                 + ((part[4][l][v] + part[5][l][v]) + (part[6][l][v] + part[7][l][v])));
        out[(b * LQ_ + l0 + l) * H_ + v] = o * rinvs[l];
    }
}

extern "C" void kernel_launch(void* const* d_in, const int* in_sizes, int n_in,
                              void* d_out, int out_size, void* d_ws, size_t ws_size,
                              hipStream_t stream) {
    const float* queries    = (const float*)d_in[0];
    const float* keys       = (const float*)d_in[1];
    const float* values     = (const float*)d_in[2];
    const int*   valid_lens = (const int*)d_in[3];
    const float* W_q        = (const float*)d_in[4];
    const float* W_k        = (const float*)d_in[5];
    const float* w_v        = (const float*)d_in[6];
    float* out = (float*)d_out;
    (void)d_ws; (void)ws_size; (void)in_sizes; (void)n_in; (void)out_size;

    proj_kernel <<<288, 256, 0, stream>>>(queries, keys, W_q, W_k);
    score_kernel<<<2048, 128, 0, stream>>>(valid_lens, w_v);
    smpv_kernel <<<512, 512, 0, stream>>>(values, valid_lens, out);
}

// Round 12
// 48.785 us; speedup vs baseline: 2.0597x; 2.0597x over previous
//
#include <hip/hip_runtime.h>
#include <hip/hip_bf16.h>

#define B_   8
#define LQ_  128
#define LK_  1024
#define H_   128

// tanh(q+k) = 1 - 2/(EQ*EK + 1) with EQ=exp(2q'), EK=exp(2k').
// g_ekT is TRANSPOSED: [b][h][s] so the score kernel's inner loads are
// coalesced (lane stride 16B). g_eq stays [row][h] (block-uniform reads).
__device__ float g_eq [B_ * LQ_ * H_];
__device__ float g_ekT[B_ * H_ * LK_];
__device__ float g_sc [B_ * LQ_ * LK_];  // raw scores, only [0,valid) written

#define C2LOG2E 2.8853900817779268f      // 2/ln2

// Tiled projection (R8-proven staging). Q path: row-major exp. K path:
// register-transposed store into g_ekT + exp. Branch is block-uniform.
__global__ __launch_bounds__(256) void proj_kernel(const float* __restrict__ q,
                                                   const float* __restrict__ k,
                                                   const float* __restrict__ Wq,
                                                   const float* __restrict__ Wk) {
    __shared__ float Ws[H_ * H_];
    __shared__ float Xs[32 * H_];
    const int t = threadIdx.x;
    const int tile = blockIdx.x;
    const bool isq = (tile < 32);
    const float* X; const float* W; int r0;
    if (isq) { X = q; W = Wq; r0 = tile * 32; }
    else     { X = k; W = Wk; r0 = (tile - 32) * 32; }

    #pragma unroll
    for (int u = 0; u < 16; ++u) {
        int idx = u * 256 + t;
        *(float4*)(Ws + idx * 4) = *(const float4*)(W + idx * 4);
    }
    #pragma unroll
    for (int u = 0; u < 4; ++u) {
        int idx = u * 256 + t;
        int r = idx >> 5, c = idx & 31;
        *(float4*)(Xs + r * H_ + c * 4) = *(const float4*)(X + (r0 + r) * H_ + c * 4);
    }
    __syncthreads();

    const int r4 = t >> 5;               // [0,8)
    const int c4 = t & 31;               // [0,32)
    float acc[4][4] = {};
    #pragma unroll 4
    for (int kk = 0; kk < H_; ++kk) {
        float4 w4 = *(const float4*)(Ws + kk * H_ + c4 * 4);
        #pragma unroll
        for (int i = 0; i < 4; ++i) {
            float x = Xs[(r4 * 4 + i) * H_ + kk];
            acc[i][0] = fmaf(x, w4.x, acc[i][0]);
            acc[i][1] = fmaf(x, w4.y, acc[i][1]);
            acc[i][2] = fmaf(x, w4.z, acc[i][2]);
            acc[i][3] = fmaf(x, w4.w, acc[i][3]);
        }
    }
    if (isq) {
        #pragma unroll
        for (int i = 0; i < 4; ++i) {
            float4 o;
            o.x = __builtin_amdgcn_exp2f(acc[i][0] * C2LOG2E);
            o.y = __builtin_amdgcn_exp2f(acc[i][1] * C2LOG2E);
            o.z = __builtin_amdgcn_exp2f(acc[i][2] * C2LOG2E);
            o.w = __builtin_amdgcn_exp2f(acc[i][3] * C2LOG2E);
            *(float4*)(g_eq + (size_t)(r0 + r4 * 4 + i) * H_ + c4 * 4) = o;
        }
    } else {
        const int b = r0 >> 10;          // 32-row tile never straddles b
        const int sb = (r0 & 1023) + r4 * 4;
        #pragma unroll
        for (int j = 0; j < 4; ++j) {    // h = c4*4+j; s = sb..sb+3 contiguous
            float4 o;
            o.x = __builtin_amdgcn_exp2f(acc[0][j] * C2LOG2E);
            o.y = __builtin_amdgcn_exp2f(acc[1][j] * C2LOG2E);
            o.z = __builtin_amdgcn_exp2f(acc[2][j] * C2LOG2E);
            o.w = __builtin_amdgcn_exp2f(acc[3][j] * C2LOG2E);
            *(float4*)(g_ekT + ((size_t)b * H_ + (c4 * 4 + j)) * LK_ + sb) = o;
        }
    }
}

// Scores: one block per (b,l) row, 256 threads, thread owns 4 CONSECUTIVE s.
// h-loop: ekT[h][s0..s0+3] load is fully coalesced (lane stride 16B);
// q[h], w[h] are block-uniform (scalar loads). 4 independent acc streams.
// score = wsum - 2 * sum_h w_h * rcp(EQ_h*EK_h + 1). Writes disjoint.
__global__ __launch_bounds__(256) void score_kernel(const int* __restrict__ valid_lens,
                                                    const float* __restrict__ w_v) {
    const int row = blockIdx.x;              // b*LQ + l
    const int b = row >> 7;
    int valid = valid_lens[b];
    valid = min(max(valid, 0), LK_);
    const int s0 = threadIdx.x << 2;
    if (s0 >= valid) return;                 // waves past valid retire early
    int nj = valid - s0;
    nj = min(nj, 4);

    const float* __restrict__ qrow = g_eq + (size_t)row * H_;
    const float* __restrict__ ek   = g_ekT + (size_t)b * H_ * LK_ + s0;

    float a0 = 0.0f, a1 = 0.0f, a2 = 0.0f, a3 = 0.0f, wsum = 0.0f;
    #pragma unroll 4
    for (int h = 0; h < H_; ++h) {
        const float qh = qrow[h];
        const float wh = w_v[h];
        wsum += wh;
        float4 e = *(const float4*)(ek + (size_t)h * LK_);
        a0 = fmaf(wh, __builtin_amdgcn_rcpf(fmaf(qh, e.x, 1.0f)), a0);
        a1 = fmaf(wh, __builtin_amdgcn_rcpf(fmaf(qh, e.y, 1.0f)), a1);
        a2 = fmaf(wh, __builtin_amdgcn_rcpf(fmaf(qh, e.z, 1.0f)), a2);
        a3 = fmaf(wh, __builtin_amdgcn_rcpf(fmaf(qh, e.w, 1.0f)), a3);
    }
    float* srow = g_sc + (size_t)row * LK_;
    float r0 = fmaf(-2.0f, a0, wsum);
    float r1 = fmaf(-2.0f, a1, wsum);
    float r2 = fmaf(-2.0f, a2, wsum);
    float r3 = fmaf(-2.0f, a3, wsum);
    if (nj == 4) {
        *(float4*)(srow + s0) = make_float4(r0, r1, r2, r3);
    } else {
        if (nj > 0) srow[s0] = r0;
        if (nj > 1) srow[s0 + 1] = r1;
        if (nj > 2) srow[s0 + 2] = r2;
    }
}

// Softmax + PV, 2 rows per block (512 x 512). Byte-identical to green R11.
__global__ __launch_bounds__(512) void smpv_kernel(const float* __restrict__ values,
                                                   const int* __restrict__ valid_lens,
                                                   float* __restrict__ out) {
    __shared__ float sA[LK_], sB[LK_];
    __shared__ float red[8], sred[16];
    __shared__ float rinvs[2];
    __shared__ float part[8][2][H_];
    const int t = threadIdx.x;
    const int b = blockIdx.x >> 6, l0 = (blockIdx.x & 63) * 2;
    int valid = valid_lens[b];
    valid = min(max(valid, 0), LK_);

    const float* src = g_sc + (size_t)(b * LQ_ + l0) * LK_;
    for (int i = t; i < valid; i += 512) { sA[i] = src[i]; sB[i] = src[LK_ + i]; }
    __syncthreads();

    int n;
    if (valid == 0) {                         // ref: all -1e6 -> uniform
        n = LK_;
        for (int i = t; i < LK_; i += 512) { sA[i] = 1.0f; sB[i] = 1.0f; }
        if (t == 0) { rinvs[0] = 1.0f / 1024.0f; rinvs[1] = 1.0f / 1024.0f; }
    } else {
        n = valid;
        const int r = t >> 8, tt = t & 255;   // 256 threads per row
        const int w4id = tt >> 6;
        float* srow = r ? sB : sA;
        float m = -3.0e38f;
        for (int i = tt; i < n; i += 256) m = fmaxf(m, srow[i]);
        #pragma unroll
        for (int kk = 32; kk; kk >>= 1) m = fmaxf(m, __shfl_xor(m, kk, 64));
        if ((tt & 63) == 0) red[r * 4 + w4id] = m;
        __syncthreads();
        m = fmaxf(fmaxf(red[r * 4], red[r * 4 + 1]), fmaxf(red[r * 4 + 2], red[r * 4 + 3]));
        float ps = 0.0f;
        for (int i = tt; i < n; i += 256) {
            float e = __builtin_amdgcn_exp2f((srow[i] - m) * 1.44269504f);
            srow[i] = e;
            ps += e;
        }
        #pragma unroll
        for (int kk = 32; kk; kk >>= 1) ps += __shfl_xor(ps, kk, 64);
        if ((tt & 63) == 0) sred[r * 4 + w4id] = ps;
        __syncthreads();
        if (t < 2) {
            float s4 = (sred[t * 4] + sred[t * 4 + 1]) + (sred[t * 4 + 2] + sred[t * 4 + 3]);
            rinvs[t] = 1.0f / s4;
        }
    }
    __syncthreads();

    const int c = t >> 6;
    const int v2 = t & 63;
    const float* vb = values + (size_t)b * LK_ * H_ + 2 * v2;
    float ax0 = 0.0f, ay0 = 0.0f, ax1 = 0.0f, ay1 = 0.0f;
    #pragma unroll 4
    for (int s = c; s < n; s += 8) {
        float2 vv = *(const float2*)(vb + (size_t)s * H_);
        float w0 = sA[s], w1 = sB[s];
        ax0 = fmaf(w0, vv.x, ax0); ay0 = fmaf(w0, vv.y, ay0);
        ax1 = fmaf(w1, vv.x, ax1); ay1 = fmaf(w1, vv.y, ay1);
    }
    *(float2*)(&part[c][0][2 * v2]) = make_float2(ax0, ay0);
    *(float2*)(&part[c][1][2 * v2]) = make_float2(ax1, ay1);
    __syncthreads();
    if (t < 256) {
        const int l = t >> 7, v = t & 127;
        float o = (((part[0][l][v] + part[1][l][v]) + (part[2][l][v] + part[3][l][v]))
                 + ((part[4][l][v] + part[5][l][v]) + (part[6][l][v] + part[7][l][v])));
        out[(b * LQ_ + l0 + l) * H_ + v] = o * rinvs[l];
    }
}

extern "C" void kernel_launch(void* const* d_in, const int* in_sizes, int n_in,
                              void* d_out, int out_size, void* d_ws, size_t ws_size,
                              hipStream_t stream) {
    const float* queries    = (const float*)d_in[0];
    const float* keys       = (const float*)d_in[1];
    const float* values     = (const float*)d_in[2];
    const int*   valid_lens = (const int*)d_in[3];
    const float* W_q        = (const float*)d_in[4];
    const float* W_k        = (const float*)d_in[5];
    const float* w_v        = (const float*)d_in[6];
    float* out = (float*)d_out;
    (void)d_ws; (void)ws_size; (void)in_sizes; (void)n_in; (void)out_size;

    proj_kernel <<<288, 256, 0, stream>>>(queries, keys, W_q, W_k);
    score_kernel<<<B_ * LQ_, 256, 0, stream>>>(valid_lens, w_v);
    smpv_kernel <<<512, 512, 0, stream>>>(values, valid_lens, out);
}

// Round 13
// 41.044 us; speedup vs baseline: 2.4481x; 1.1886x over previous
//
#include <hip/hip_runtime.h>
#include <hip/hip_fp16.h>

#define B_   8
#define LQ_  128
#define LK_  1024
#define H_   128

// tanh(q+k) = 1 - 2/(EQ*EK + 1), EQ=exp(2q') f32, EK=exp(2k') stored f16
// TRANSPOSED [b][h][s] packed as half2 (uint): score loads are half2/lane,
// wave = 256B contiguous. f16 EK: k'~N(0,1); saturation (|k'|>5.5) yields
// tanh -> +/-1 which is the correct limit; rel err 2^-11 -> score err ~2e-4.
__device__ float        g_eq  [B_ * LQ_ * H_];
__device__ unsigned int g_ekT2[B_ * H_ * (LK_ / 2)];   // half2-packed

#define C2LOG2E 2.8853900817779268f      // 2/ln2

// Tiled projection, column-split: grid (288, 2), 48KB LDS -> 3 blocks/CU.
// Blocks [0,32) of x: queries -> g_eq; [32,288): keys -> g_ekT2 (f16 pack,
// register transpose). Thread = (r4 = t>>5: 4 rows, tc = t&31: 2 cols).
__global__ __launch_bounds__(256) void proj_kernel(const float* __restrict__ q,
                                                   const float* __restrict__ k,
                                                   const float* __restrict__ Wq,
                                                   const float* __restrict__ Wk) {
    __shared__ float Ws[H_ * 64];        // 32 KB: W columns [ch*64, ch*64+64)
    __shared__ float Xs[32 * H_];        // 16 KB
    const int t = threadIdx.x;
    const int tile = blockIdx.x;
    const int ch = blockIdx.y;           // column half
    const bool isq = (tile < 32);
    const float* X; const float* W; int r0;
    if (isq) { X = q; W = Wq; r0 = tile * 32; }
    else     { X = k; W = Wk; r0 = (tile - 32) * 32; }

    // stage W half: 128 x 64 = 2048 float4, 8/thread
    #pragma unroll
    for (int u = 0; u < 8; ++u) {
        int p = u * 256 + t;
        int kk = p >> 4, c4 = p & 15;
        *(float4*)(Ws + kk * 64 + c4 * 4) = *(const float4*)(W + kk * H_ + ch * 64 + c4 * 4);
    }
    #pragma unroll
    for (int u = 0; u < 4; ++u) {
        int idx = u * 256 + t;
        int r = idx >> 5, c = idx & 31;
        *(float4*)(Xs + r * H_ + c * 4) = *(const float4*)(X + (size_t)(r0 + r) * H_ + c * 4);
    }
    __syncthreads();

    const int r4 = t >> 5;               // [0,8): 4-row group
    const int tc = t & 31;               // [0,32): 2-col group
    float acc[4][2] = {};
    #pragma unroll 4
    for (int kk = 0; kk < H_; ++kk) {
        float2 w2 = *(const float2*)(Ws + kk * 64 + tc * 2);
        #pragma unroll
        for (int i = 0; i < 4; ++i) {
            float x = Xs[(r4 * 4 + i) * H_ + kk];
            acc[i][0] = fmaf(x, w2.x, acc[i][0]);
            acc[i][1] = fmaf(x, w2.y, acc[i][1]);
        }
    }
    if (isq) {
        #pragma unroll
        for (int i = 0; i < 4; ++i) {
            float2 o;
            o.x = __builtin_amdgcn_exp2f(acc[i][0] * C2LOG2E);
            o.y = __builtin_amdgcn_exp2f(acc[i][1] * C2LOG2E);
            *(float2*)(g_eq + (size_t)(r0 + r4 * 4 + i) * H_ + ch * 64 + tc * 2) = o;
        }
    } else {
        const int b = r0 >> 10;          // 32-row tile never straddles b
        const int sb = (r0 & 1023) + r4 * 4;     // 4 consecutive s
        #pragma unroll
        for (int j = 0; j < 2; ++j) {    // h = ch*64 + tc*2 + j
            const int h = ch * 64 + tc * 2 + j;
            float e0 = __builtin_amdgcn_exp2f(acc[0][j] * C2LOG2E);
            float e1 = __builtin_amdgcn_exp2f(acc[1][j] * C2LOG2E);
            float e2 = __builtin_amdgcn_exp2f(acc[2][j] * C2LOG2E);
            float e3 = __builtin_amdgcn_exp2f(acc[3][j] * C2LOG2E);
            __half2 p0 = __floats2half2_rn(e0, e1);
            __half2 p1 = __floats2half2_rn(e2, e3);
            uint2 pk = make_uint2(*(unsigned int*)&p0, *(unsigned int*)&p1);
            *(uint2*)(g_ekT2 + (size_t)(b * H_ + h) * (LK_ / 2) + (sb >> 1)) = pk;
        }
    }
}

// Fused scores + masked softmax + PV, 2 q-rows per block (512 x 512).
// Phase 1: thread owns s in {2t, 2t+1}: ONE half2 EK load per h (wave=256B
// contiguous); eq0/eq1/w_v reads are block-uniform (scalar). 4 rcp streams.
// Whole-wave skip when 2t >= valid. Phase 2/3: R11/R12-proven patterns.
__global__ __launch_bounds__(512) void fused_attn(const float* __restrict__ values,
                                                  const int* __restrict__ valid_lens,
                                                  const float* __restrict__ w_v,
                                                  float* __restrict__ out) {
    __shared__ float sA[LK_], sB[LK_];
    __shared__ float red[8], sred[16];
    __shared__ float rinvs[2];
    __shared__ float part[8][2][H_];
    const int t = threadIdx.x;
    const int b = blockIdx.x >> 6, l0 = (blockIdx.x & 63) * 2;
    int valid = valid_lens[b];
    valid = min(max(valid, 0), LK_);

    // ---- Phase 1: scores for s < valid ----
    const int s0 = 2 * t;                // 0..1022
    if (s0 < valid) {
        const float* __restrict__ q0 = g_eq + (size_t)(b * LQ_ + l0) * H_;
        const float* __restrict__ q1 = q0 + H_;
        const unsigned int* __restrict__ ek = g_ekT2 + (size_t)b * H_ * (LK_ / 2) + t;
        float a00 = 0.0f, a01 = 0.0f, a10 = 0.0f, a11 = 0.0f, wsum = 0.0f;
        #pragma unroll 4
        for (int h = 0; h < H_; ++h) {
            unsigned int u = ek[(size_t)h * (LK_ / 2)];
            float2 ef = __half22float2(*(const __half2*)&u);
            const float e0 = ef.x, e1 = ef.y;
            const float qa = q0[h], qb = q1[h], wh = w_v[h];
            wsum += wh;
            a00 = fmaf(wh, __builtin_amdgcn_rcpf(fmaf(qa, e0, 1.0f)), a00);
            a01 = fmaf(wh, __builtin_amdgcn_rcpf(fmaf(qa, e1, 1.0f)), a01);
            a10 = fmaf(wh, __builtin_amdgcn_rcpf(fmaf(qb, e0, 1.0f)), a10);
            a11 = fmaf(wh, __builtin_amdgcn_rcpf(fmaf(qb, e1, 1.0f)), a11);
        }
        *(float2*)(sA + s0) = make_float2(fmaf(-2.0f, a00, wsum), fmaf(-2.0f, a01, wsum));
        *(float2*)(sB + s0) = make_float2(fmaf(-2.0f, a10, wsum), fmaf(-2.0f, a11, wsum));
    }
    __syncthreads();

    // ---- Phase 2: masked softmax (weights in sA/sB, 1/sum in rinvs) ----
    int n;
    if (valid == 0) {                    // ref: all -1e6 -> uniform
        n = LK_;
        for (int i = t; i < LK_; i += 512) { sA[i] = 1.0f; sB[i] = 1.0f; }
        if (t == 0) { rinvs[0] = 1.0f / 1024.0f; rinvs[1] = 1.0f / 1024.0f; }
    } else {
        n = valid;
        const int r = t >> 8, tt = t & 255;      // 256 threads per row
        const int w4id = tt >> 6;
        float* srow = r ? sB : sA;
        float m = -3.0e38f;
        for (int i = tt; i < n; i += 256) m = fmaxf(m, srow[i]);
        #pragma unroll
        for (int kk = 32; kk; kk >>= 1) m = fmaxf(m, __shfl_xor(m, kk, 64));
        if ((tt & 63) == 0) red[r * 4 + w4id] = m;
        __syncthreads();
        m = fmaxf(fmaxf(red[r * 4], red[r * 4 + 1]), fmaxf(red[r * 4 + 2], red[r * 4 + 3]));
        float ps = 0.0f;
        for (int i = tt; i < n; i += 256) {
            float e = __builtin_amdgcn_exp2f((srow[i] - m) * 1.44269504f);
            srow[i] = e;
            ps += e;
        }
        #pragma unroll
        for (int kk = 32; kk; kk >>= 1) ps += __shfl_xor(ps, kk, 64);
        if ((tt & 63) == 0) sred[r * 4 + w4id] = ps;
        __syncthreads();
        if (t < 2) {
            float s4 = (sred[t * 4] + sred[t * 4 + 1]) + (sred[t * 4 + 2] + sred[t * 4 + 3]);
            rinvs[t] = 1.0f / s4;
        }
    }
    __syncthreads();

    // ---- Phase 3: PV, float2 values loads feed both rows, 8-way s-split ----
    const int c = t >> 6;
    const int v2 = t & 63;
    const float* vb = values + (size_t)b * LK_ * H_ + 2 * v2;
    float ax0 = 0.0f, ay0 = 0.0f, ax1 = 0.0f, ay1 = 0.0f;
    #pragma unroll 4
    for (int s = c; s < n; s += 8) {
        float2 vv = *(const float2*)(vb + (size_t)s * H_);
        float w0 = sA[s], w1 = sB[s];
        ax0 = fmaf(w0, vv.x, ax0); ay0 = fmaf(w0, vv.y, ay0);
        ax1 = fmaf(w1, vv.x, ax1); ay1 = fmaf(w1, vv.y, ay1);
    }
    *(float2*)(&part[c][0][2 * v2]) = make_float2(ax0, ay0);
    *(float2*)(&part[c][1][2 * v2]) = make_float2(ax1, ay1);
    __syncthreads();
    if (t < 256) {
        const int l = t >> 7, v = t & 127;
        float o = (((part[0][l][v] + part[1][l][v]) + (part[2][l][v] + part[3][l][v]))
                 + ((part[4][l][v] + part[5][l][v]) + (part[6][l][v] + part[7][l][v])));
        out[(b * LQ_ + l0 + l) * H_ + v] = o * rinvs[l];
    }
}

extern "C" void kernel_launch(void* const* d_in, const int* in_sizes, int n_in,
                              void* d_out, int out_size, void* d_ws, size_t ws_size,
                              hipStream_t stream) {
    const float* queries    = (const float*)d_in[0];
    const float* keys       = (const float*)d_in[1];
    const float* values     = (const float*)d_in[2];
    const int*   valid_lens = (const int*)d_in[3];
    const float* W_q        = (const float*)d_in[4];
    const float* W_k        = (const float*)d_in[5];
    const float* w_v        = (const float*)d_in[6];
    float* out = (float*)d_out;
    (void)d_ws; (void)ws_size; (void)in_sizes; (void)n_in; (void)out_size;

    proj_kernel<<<dim3(288, 2), 256, 0, stream>>>(queries, keys, W_q, W_k);
    fused_attn <<<512, 512, 0, stream>>>(values, valid_lens, w_v, out);
}